// Round 6
// baseline (233.374 us; speedup 1.0000x reference)
//
#include <hip/hip_runtime.h>
#include <math.h>

#define NG   16
#define HID  256
#define TPTS 4096                    // table intervals; TPTS+1 entries in d_ws

typedef float f32x4 __attribute__((ext_vector_type(4)));

constexpr size_t BT      = 32ull * 2048ull;            // 65536 rows
constexpr size_t TOK_OFF = BT * HID;
constexpr size_t WT_OFF  = TOK_OFF + BT * NG * HID;
constexpr float  ZLO = -10.0f, ZHI = 10.0f;
constexpr float  ZSTEP  = (ZHI - ZLO) / TPTS;
constexpr float  ZSCALE = TPTS / (ZHI - ZLO);

__device__ __forceinline__ float rln(float v, int l) {  // const-lane -> SGPR
    return __int_as_float(__builtin_amdgcn_readlane(__float_as_int(v), l));
}

// ---- kernel 1: tabulate F(z) = sum_h tanh(z*w_gp[h]+b_gp[h])*w_sp[h] + b_sp
// Row-independent scalar function of the group-mean; 4097 pts, lerp err ~3e-7.
__global__ __launch_bounds__(256) void build_table(
    const float* __restrict__ w_gp, const float* __restrict__ b_gp,
    const float* __restrict__ w_sp, const float* __restrict__ b_sp,
    float* __restrict__ tbl)
{
    const int i = blockIdx.x * 256 + threadIdx.x;
    if (i > TPTS) return;
    const float z = ZLO + (float)i * ZSTEP;
    float s = b_sp[0];
    for (int h = 0; h < HID; ++h)
        s += tanhf(fmaf(z, w_gp[h], b_gp[h])) * w_sp[h];
    tbl[i] = s;
}

// ---- kernel 2: main. 1 wave = 4 rows; lane = (row j = lane>>4, group g = lane&15)
__global__ __launch_bounds__(256) void gve_kernel(
    const float*  __restrict__ x,      // (BT,64)
    const f32x4*  __restrict__ w_gp4,  // (64) float4
    const f32x4*  __restrict__ b_gp4,
    const float*  __restrict__ tbl,    // (TPTS+1) score table
    float* __restrict__ out)
{
    const int lane = threadIdx.x & 63;
    const int wv   = threadIdx.x >> 6;
    const size_t row0 = ((size_t)blockIdx.x * 4 + wv) * 4;  // 4 rows per wave

    // ---- one coalesced 1 KB load = this wave's 4 x-rows; stage in LDS ----
    __shared__ float sx[4][4][68];     // +4 pad: de-conflict per-row reads
    {
        const f32x4 xl = ((const f32x4*)x)[row0 * 16 + lane];
        const int r = lane >> 4, c = lane & 15;       // float 4*lane -> row r
        *(f32x4*)&sx[wv][r][c * 4] = xl;              // 16B-aligned (68=17*4)
    }
    // intra-wave producer/consumer only -> no barrier (lgkmcnt ordered)

    const int j   = lane >> 4;         // row within wave
    const int g   = lane & 15;         // group
    const int sub = g & 3;             // segment sizes [1,3,5,7] tiled x4
    const int sz  = 2 * sub + 1;
    const int beg = ((g >> 2) << 4) + sub * sub;      // starts {0,1,4,9}+16*chunk

    // ---- group mean for (row j, group g) ----
    float s = 0.0f;
    #pragma unroll
    for (int i = 0; i < 7; ++i)
        if (i < sz) s += sx[wv][j][beg + i];
    const float gv = s * __builtin_amdgcn_rcpf((float)sz);  // exact for sz=1

    // ---- score via table lookup + lerp (replaces 256 tanh) ----
    float idxf = fminf(fmaxf((gv - ZLO) * ZSCALE, 0.0f), (float)TPTS - 0.001f);
    const int   i0 = (int)idxf;
    const float fr = idxf - (float)i0;
    const float t0 = tbl[i0], t1 = tbl[i0 + 1];
    const float score = fmaf(fr, t1 - t0, t0);

    // ---- softmax across the 16-lane group (xor 1,2,4,8 stays in-group) ----
    float m = score;
    m = fmaxf(m, __shfl_xor(m, 1, 64));
    m = fmaxf(m, __shfl_xor(m, 2, 64));
    m = fmaxf(m, __shfl_xor(m, 4, 64));
    m = fmaxf(m, __shfl_xor(m, 8, 64));
    const float e = __expf(score - m);
    float ssum = e;
    ssum += __shfl_xor(ssum, 1, 64);
    ssum += __shfl_xor(ssum, 2, 64);
    ssum += __shfl_xor(ssum, 4, 64);
    ssum += __shfl_xor(ssum, 8, 64);
    const float w = e / ssum;          // weight for (row j, group g)

    // ---- weights: one fully-active 256 B NT store for all 4 rows ----
    __builtin_nontemporal_store(w, out + WT_OFF + row0 * NG + lane);

    // ---- dot_j = sum_g wt_g * gv_g (visit = dot*w_gp + b_gp, exactly) ----
    float d = w * gv;
    d += __shfl_xor(d, 1, 64);
    d += __shfl_xor(d, 2, 64);
    d += __shfl_xor(d, 4, 64);
    d += __shfl_xor(d, 8, 64);         // every lane holds dot for its row j

    // ---- per-lane hidden slice h = 4*lane..4*lane+3 ----
    const f32x4 wg = w_gp4[lane];
    const f32x4 bg = b_gp4[lane];

    #pragma unroll
    for (int jj = 0; jj < 4; ++jj) {
        const size_t row = row0 + jj;

        // visit row: dot_jj broadcast from lane jj*16 (const lane -> SGPR)
        const float dj = rln(d, jj * 16);
        f32x4 vis;
        vis.x = fmaf(dj, wg.x, bg.x);
        vis.y = fmaf(dj, wg.y, bg.y);
        vis.z = fmaf(dj, wg.z, bg.z);
        vis.w = fmaf(dj, wg.w, bg.w);
        __builtin_nontemporal_store(vis, (f32x4*)(out + row * HID + 4 * lane));

        // token rows: gv_{jj,g2} broadcast via const-lane readlane
        float* __restrict__ tokp = out + TOK_OFF + row * (NG * HID) + 4 * lane;
        #pragma unroll
        for (int g2 = 0; g2 < NG; ++g2) {
            const float gvj = rln(gv, jj * 16 + g2);
            f32x4 t;
            t.x = fmaf(gvj, wg.x, bg.x);
            t.y = fmaf(gvj, wg.y, bg.y);
            t.z = fmaf(gvj, wg.z, bg.z);
            t.w = fmaf(gvj, wg.w, bg.w);
            __builtin_nontemporal_store(t, (f32x4*)(tokp + g2 * HID));
        }
    }
}

extern "C" void kernel_launch(void* const* d_in, const int* in_sizes, int n_in,
                              void* d_out, int out_size, void* d_ws, size_t ws_size,
                              hipStream_t stream) {
    (void)in_sizes; (void)n_in; (void)out_size; (void)ws_size;
    const float* x    = (const float*)d_in[0];
    const float* w_gp = (const float*)d_in[1];
    const float* b_gp = (const float*)d_in[2];
    const float* w_sp = (const float*)d_in[3];
    const float* b_sp = (const float*)d_in[4];
    float* out = (float*)d_out;
    float* tbl = (float*)d_ws;          // needs (TPTS+1)*4 = 16388 B of scratch

    build_table<<<dim3((TPTS + 256) / 256), dim3(256), 0, stream>>>(
        w_gp, b_gp, w_sp, b_sp, tbl);   // same stream -> ordered before main

    gve_kernel<<<dim3((unsigned)(BT / 16)), dim3(256), 0, stream>>>(
        x, (const f32x4*)w_gp, (const f32x4*)b_gp, tbl, out);
}

// Round 7
// 228.812 us; speedup vs baseline: 1.0199x; 1.0199x over previous
//
#include <hip/hip_runtime.h>
#include <math.h>

#define NG   16
#define HID  256
#define TPTS 4096                    // table intervals; TPTS+1 entries in d_ws

typedef float f32x4 __attribute__((ext_vector_type(4)));

constexpr size_t BT      = 32ull * 2048ull;            // 65536 rows
constexpr size_t TOK_OFF = BT * HID;
constexpr size_t WT_OFF  = TOK_OFF + BT * NG * HID;
constexpr float  ZLO = -10.0f, ZHI = 10.0f;
constexpr float  ZSTEP  = (ZHI - ZLO) / TPTS;
constexpr float  ZSCALE = TPTS / (ZHI - ZLO);

__device__ __forceinline__ float rln(float v, int l) {  // const-lane -> SGPR
    return __int_as_float(__builtin_amdgcn_readlane(__float_as_int(v), l));
}

// ---- kernel 1: tabulate F(z) = sum_h tanh(z*w_gp[h]+b_gp[h])*w_sp[h] + b_sp
__global__ __launch_bounds__(256) void build_table(
    const float* __restrict__ w_gp, const float* __restrict__ b_gp,
    const float* __restrict__ w_sp, const float* __restrict__ b_sp,
    float* __restrict__ tbl)
{
    const int i = blockIdx.x * 256 + threadIdx.x;
    if (i > TPTS) return;
    const float z = ZLO + (float)i * ZSTEP;
    float s = b_sp[0];
    for (int h = 0; h < HID; ++h)
        s += tanhf(fmaf(z, w_gp[h], b_gp[h])) * w_sp[h];
    tbl[i] = s;
}

// ---- kernel 2: block = 16 rows. Compute phase per wave (4 rows), then a
// block-cooperative DENSE sweep of the 256 KB token region (4 KB front).
__global__ __launch_bounds__(256) void gve_kernel(
    const float*  __restrict__ x,      // (BT,64)
    const f32x4*  __restrict__ w_gp4,  // (64) float4
    const f32x4*  __restrict__ b_gp4,
    const float*  __restrict__ tbl,    // (TPTS+1) score table
    float* __restrict__ out)
{
    const int lane = threadIdx.x & 63;
    const int wv   = threadIdx.x >> 6;
    const size_t brow0 = (size_t)blockIdx.x * 16;     // block owns 16 rows
    const size_t row0  = brow0 + (size_t)wv * 4;      // wave computes 4 rows

    __shared__ float sx[4][4][68];    // per-wave x staging (+pad)
    __shared__ float sgv[16][16];     // block's group means: [row][g]

    // ---- one coalesced 1 KB load = this wave's 4 x-rows ----
    {
        const f32x4 xl = ((const f32x4*)x)[row0 * 16 + lane];
        const int r = lane >> 4, c = lane & 15;
        *(f32x4*)&sx[wv][r][c * 4] = xl;              // 16B aligned (68=17*4)
    }
    // intra-wave producer/consumer only here (lgkmcnt-ordered)

    const int j   = lane >> 4;        // row within wave's quad
    const int g   = lane & 15;        // group
    const int sub = g & 3;            // segment sizes [1,3,5,7] tiled x4
    const int sz  = 2 * sub + 1;
    const int beg = ((g >> 2) << 4) + sub * sub;      // {0,1,4,9}+16*chunk

    // ---- group mean for (row j, group g) ----
    float s = 0.0f;
    #pragma unroll
    for (int i = 0; i < 7; ++i)
        if (i < sz) s += sx[wv][j][beg + i];
    const float gv = s * __builtin_amdgcn_rcpf((float)sz);

    sgv[wv * 4 + j][g] = gv;          // publish for the token sweep

    // ---- score via table lookup + lerp ----
    float idxf = fminf(fmaxf((gv - ZLO) * ZSCALE, 0.0f), (float)TPTS - 0.001f);
    const int   i0 = (int)idxf;
    const float fr = idxf - (float)i0;
    const float t0 = tbl[i0], t1 = tbl[i0 + 1];
    const float score = fmaf(fr, t1 - t0, t0);

    // ---- softmax across the 16-lane group ----
    float m = score;
    m = fmaxf(m, __shfl_xor(m, 1, 64));
    m = fmaxf(m, __shfl_xor(m, 2, 64));
    m = fmaxf(m, __shfl_xor(m, 4, 64));
    m = fmaxf(m, __shfl_xor(m, 8, 64));
    const float e = __expf(score - m);
    float ssum = e;
    ssum += __shfl_xor(ssum, 1, 64);
    ssum += __shfl_xor(ssum, 2, 64);
    ssum += __shfl_xor(ssum, 4, 64);
    ssum += __shfl_xor(ssum, 8, 64);
    const float w = e / ssum;         // weight for (row j, group g)

    // ---- weights: fully-active 256 B NT store for the wave's 4 rows ----
    __builtin_nontemporal_store(w, out + WT_OFF + row0 * NG + lane);

    // ---- dot_j = sum_g wt_g * gv_g ; visit = dot*w_gp + b_gp (exact) ----
    float d = w * gv;
    d += __shfl_xor(d, 1, 64);
    d += __shfl_xor(d, 2, 64);
    d += __shfl_xor(d, 4, 64);
    d += __shfl_xor(d, 8, 64);

    const f32x4 wg = w_gp4[lane];
    const f32x4 bg = b_gp4[lane];

    #pragma unroll
    for (int jj = 0; jj < 4; ++jj) {
        const float dj = rln(d, jj * 16);
        f32x4 vis;
        vis.x = fmaf(dj, wg.x, bg.x);
        vis.y = fmaf(dj, wg.y, bg.y);
        vis.z = fmaf(dj, wg.z, bg.z);
        vis.w = fmaf(dj, wg.w, bg.w);
        __builtin_nontemporal_store(vis,
            (f32x4*)(out + (row0 + jj) * HID + 4 * lane));
    }

    __syncthreads();                  // sgv ready for all waves

    // ---- cooperative token sweep: 256 chunks of 1 KB, dense 4 KB front ----
    // chunk c covers (row = c>>4, g = c&15, all 256 h); wave wv takes c = i*4+wv
    float* __restrict__ btok = out + TOK_OFF + brow0 * (NG * HID) + 4 * lane;
    #pragma unroll 8
    for (int i = 0; i < 64; ++i) {
        const int c = i * 4 + wv;
        const float gvv = sgv[c >> 4][c & 15];        // uniform addr: broadcast
        f32x4 t;
        t.x = fmaf(gvv, wg.x, bg.x);
        t.y = fmaf(gvv, wg.y, bg.y);
        t.z = fmaf(gvv, wg.z, bg.z);
        t.w = fmaf(gvv, wg.w, bg.w);
        __builtin_nontemporal_store(t, (f32x4*)(btok + (size_t)c * HID));
    }
}

extern "C" void kernel_launch(void* const* d_in, const int* in_sizes, int n_in,
                              void* d_out, int out_size, void* d_ws, size_t ws_size,
                              hipStream_t stream) {
    (void)in_sizes; (void)n_in; (void)out_size; (void)ws_size;
    const float* x    = (const float*)d_in[0];
    const float* w_gp = (const float*)d_in[1];
    const float* b_gp = (const float*)d_in[2];
    const float* w_sp = (const float*)d_in[3];
    const float* b_sp = (const float*)d_in[4];
    float* out = (float*)d_out;
    float* tbl = (float*)d_ws;          // (TPTS+1)*4 = 16388 B of scratch

    build_table<<<dim3((TPTS + 256) / 256), dim3(256), 0, stream>>>(
        w_gp, b_gp, w_sp, b_sp, tbl);   // same stream -> ordered before main

    gve_kernel<<<dim3((unsigned)(BT / 16)), dim3(256), 0, stream>>>(
        x, (const f32x4*)w_gp, (const f32x4*)b_gp, tbl, out);
}

// Round 8
// 223.639 us; speedup vs baseline: 1.0435x; 1.0231x over previous
//
#include <hip/hip_runtime.h>
#include <math.h>

#define NG   16
#define HID  256
#define TPTS 2048                    // table intervals; TPTS+1 entries in d_ws
#define CPB  8                       // chunks (of 16 rows) per block

typedef float f32x4 __attribute__((ext_vector_type(4)));

constexpr size_t BT      = 32ull * 2048ull;            // 65536 rows
constexpr size_t TOK_OFF = BT * HID;
constexpr size_t WT_OFF  = TOK_OFF + BT * NG * HID;
constexpr float  ZLO = -10.0f, ZHI = 10.0f;
constexpr float  ZSTEP  = (ZHI - ZLO) / TPTS;
constexpr float  ZSCALE = TPTS / (ZHI - ZLO);

__device__ __forceinline__ float rln(float v, int l) {  // const-lane -> SGPR
    return __int_as_float(__builtin_amdgcn_readlane(__float_as_int(v), l));
}

// ---- kernel 1: tabulate F(z) = sum_h tanh(z*w_gp[h]+b_gp[h])*w_sp[h] + b_sp
// One block per table point; reduce over h in-wave + LDS. ~1 us total.
__global__ __launch_bounds__(256) void build_table(
    const float* __restrict__ w_gp, const float* __restrict__ b_gp,
    const float* __restrict__ w_sp, const float* __restrict__ b_sp,
    float* __restrict__ tbl)
{
    const int i = blockIdx.x;              // 0..TPTS
    const int h = threadIdx.x;
    const float z = ZLO + (float)i * ZSTEP;
    float v = tanhf(fmaf(z, w_gp[h], b_gp[h])) * w_sp[h];
    v += __shfl_xor(v, 1, 64);
    v += __shfl_xor(v, 2, 64);
    v += __shfl_xor(v, 4, 64);
    v += __shfl_xor(v, 8, 64);
    v += __shfl_xor(v, 16, 64);
    v += __shfl_xor(v, 32, 64);
    __shared__ float sred[4];
    if ((h & 63) == 0) sred[h >> 6] = v;
    __syncthreads();
    if (h == 0) tbl[i] = sred[0] + sred[1] + sred[2] + sred[3] + b_sp[0];
}

// ---- kernel 2: 512 blocks x 128 contiguous rows (8 chunks of 16).
// Per chunk: pipelined x prefetch -> gv -> lookup/softmax -> visit/weights
// stores -> block-cooperative dense 256 KB token sweep. Per-block write
// front is a contiguous 2 MB region.
__global__ __launch_bounds__(256) void gve_kernel(
    const float*  __restrict__ x,      // (BT,64)
    const f32x4*  __restrict__ w_gp4,  // (64) float4
    const f32x4*  __restrict__ b_gp4,
    const float*  __restrict__ tbl,    // (TPTS+1) score table
    float* __restrict__ out)
{
    const int lane = threadIdx.x & 63;
    const int wv   = threadIdx.x >> 6;
    const size_t brow = (size_t)blockIdx.x * (16 * CPB);  // block's first row

    __shared__ float sx[4][4][68];    // per-wave x staging (+pad, 16B-aligned)
    __shared__ float sgv[16][16];     // chunk's group means [row][g]

    const f32x4 wg = w_gp4[lane];
    const f32x4 bg = b_gp4[lane];

    const int j   = lane >> 4;        // row within wave's quad
    const int g   = lane & 15;        // group
    const int sub = g & 3;            // segment sizes [1,3,5,7] tiled x4
    const int sz  = 2 * sub + 1;
    const int beg = ((g >> 2) << 4) + sub * sub;      // {0,1,4,9}+16*chunk
    const float rsz = __builtin_amdgcn_rcpf((float)sz);

    // prefetch chunk 0: one coalesced 1 KB load = this wave's 4 x-rows
    f32x4 xl = ((const f32x4*)x)[(brow + (size_t)wv * 4) * 16 + lane];

    for (int c = 0; c < CPB; ++c) {
        const size_t crow0 = brow + (size_t)c * 16;
        const size_t row0  = crow0 + (size_t)wv * 4;

        // ---- stage prefetched x into LDS (intra-wave only) ----
        {
            const int r = lane >> 4, col = lane & 15;
            *(f32x4*)&sx[wv][r][col * 4] = xl;
        }

        // ---- issue next chunk's x load now; hides under compute+sweep ----
        if (c + 1 < CPB)
            xl = ((const f32x4*)x)[(crow0 + 16 + (size_t)wv * 4) * 16 + lane];

        // ---- group mean for (row j, group g) ----
        float s = 0.0f;
        #pragma unroll
        for (int i = 0; i < 7; ++i)
            if (i < sz) s += sx[wv][j][beg + i];
        const float gv = s * rsz;
        sgv[wv * 4 + j][g] = gv;      // publish for the sweep

        // ---- score via table lookup + lerp ----
        float idxf = fminf(fmaxf((gv - ZLO) * ZSCALE, 0.0f),
                           (float)TPTS - 0.001f);
        const int   i0 = (int)idxf;
        const float fr = idxf - (float)i0;
        const float t0 = tbl[i0], t1 = tbl[i0 + 1];
        const float score = fmaf(fr, t1 - t0, t0);

        // ---- softmax across the 16-lane group ----
        float m = score;
        m = fmaxf(m, __shfl_xor(m, 1, 64));
        m = fmaxf(m, __shfl_xor(m, 2, 64));
        m = fmaxf(m, __shfl_xor(m, 4, 64));
        m = fmaxf(m, __shfl_xor(m, 8, 64));
        const float e = __expf(score - m);
        float ssum = e;
        ssum += __shfl_xor(ssum, 1, 64);
        ssum += __shfl_xor(ssum, 2, 64);
        ssum += __shfl_xor(ssum, 4, 64);
        ssum += __shfl_xor(ssum, 8, 64);
        const float w = e / ssum;     // weight for (row j, group g)

        // ---- weights: fully-active 256 B NT store (wave's 4 rows) ----
        __builtin_nontemporal_store(w, out + WT_OFF + row0 * NG + lane);

        // ---- dot_j = sum_g wt_g*gv_g ; visit = dot*w_gp + b_gp (exact) ----
        float d = w * gv;
        d += __shfl_xor(d, 1, 64);
        d += __shfl_xor(d, 2, 64);
        d += __shfl_xor(d, 4, 64);
        d += __shfl_xor(d, 8, 64);

        #pragma unroll
        for (int jj = 0; jj < 4; ++jj) {
            const float dj = rln(d, jj * 16);
            f32x4 vis;
            vis.x = fmaf(dj, wg.x, bg.x);
            vis.y = fmaf(dj, wg.y, bg.y);
            vis.z = fmaf(dj, wg.z, bg.z);
            vis.w = fmaf(dj, wg.w, bg.w);
            __builtin_nontemporal_store(vis,
                (f32x4*)(out + (row0 + jj) * HID + 4 * lane));
        }

        __syncthreads();              // sgv ready for all waves

        // ---- dense token sweep: 256 x 1 KB chunks, 4 KB block front ----
        float* __restrict__ btok = out + TOK_OFF + crow0 * (NG * HID) + 4 * lane;
        #pragma unroll 8
        for (int i2 = 0; i2 < 64; ++i2) {
            const int cc = i2 * 4 + wv;
            const float gvv = sgv[cc >> 4][cc & 15];  // uniform: broadcast
            f32x4 t;
            t.x = fmaf(gvv, wg.x, bg.x);
            t.y = fmaf(gvv, wg.y, bg.y);
            t.z = fmaf(gvv, wg.z, bg.z);
            t.w = fmaf(gvv, wg.w, bg.w);
            __builtin_nontemporal_store(t, (f32x4*)(btok + (size_t)cc * HID));
        }

        __syncthreads();              // protect sgv before next chunk
    }
}

extern "C" void kernel_launch(void* const* d_in, const int* in_sizes, int n_in,
                              void* d_out, int out_size, void* d_ws, size_t ws_size,
                              hipStream_t stream) {
    (void)in_sizes; (void)n_in; (void)out_size; (void)ws_size;
    const float* x    = (const float*)d_in[0];
    const float* w_gp = (const float*)d_in[1];
    const float* b_gp = (const float*)d_in[2];
    const float* w_sp = (const float*)d_in[3];
    const float* b_sp = (const float*)d_in[4];
    float* out = (float*)d_out;
    float* tbl = (float*)d_ws;          // (TPTS+1)*4 = 8196 B of scratch

    build_table<<<dim3(TPTS + 1), dim3(256), 0, stream>>>(
        w_gp, b_gp, w_sp, b_sp, tbl);   // same stream -> ordered before main

    gve_kernel<<<dim3((unsigned)(BT / (16 * CPB))), dim3(256), 0, stream>>>(
        x, (const f32x4*)w_gp, (const f32x4*)b_gp, tbl, out);
}

// Round 9
// 211.107 us; speedup vs baseline: 1.1055x; 1.0594x over previous
//
#include <hip/hip_runtime.h>
#include <math.h>

#define NG   16
#define HID  256
#define TPTS 2048                    // table intervals; TPTS+1 entries in d_ws
#define GRID3 2048                   // token_sweep blocks (8192 waves)

typedef float f32x4 __attribute__((ext_vector_type(4)));

constexpr size_t BT      = 32ull * 2048ull;            // 65536 rows
constexpr size_t TOK_OFF = BT * HID;
constexpr size_t WT_OFF  = TOK_OFF + BT * NG * HID;
constexpr size_t NCHUNK  = BT * NG;                    // 1,048,576 1KB chunks
constexpr float  ZLO = -10.0f, ZHI = 10.0f;
constexpr float  ZSTEP  = (ZHI - ZLO) / TPTS;
constexpr float  ZSCALE = TPTS / (ZHI - ZLO);

__device__ __forceinline__ float rln(float v, int l) {  // const-lane -> SGPR
    return __int_as_float(__builtin_amdgcn_readlane(__float_as_int(v), l));
}

// ---- kernel 1: tabulate F(z) = sum_h tanh(z*w_gp[h]+b_gp[h])*w_sp[h] + b_sp
__global__ __launch_bounds__(256) void build_table(
    const float* __restrict__ w_gp, const float* __restrict__ b_gp,
    const float* __restrict__ w_sp, const float* __restrict__ b_sp,
    float* __restrict__ tbl)
{
    const int i = blockIdx.x;              // 0..TPTS
    const int h = threadIdx.x;
    const float z = ZLO + (float)i * ZSTEP;
    float v = tanhf(fmaf(z, w_gp[h], b_gp[h])) * w_sp[h];
    v += __shfl_xor(v, 1, 64);
    v += __shfl_xor(v, 2, 64);
    v += __shfl_xor(v, 4, 64);
    v += __shfl_xor(v, 8, 64);
    v += __shfl_xor(v, 16, 64);
    v += __shfl_xor(v, 32, 64);
    __shared__ float sred[4];
    if ((h & 63) == 0) sred[h >> 6] = v;
    __syncthreads();
    if (h == 0) tbl[i] = sred[0] + sred[1] + sred[2] + sred[3] + b_sp[0];
}

// ---- kernel 2: gv + scores + softmax + visit + weights (~95 MB traffic) ----
// wave = 4 rows; lane = (row j = lane>>4, group g = lane&15)
__global__ __launch_bounds__(256) void compute_kernel(
    const float*  __restrict__ x,      // (BT,64)
    const f32x4*  __restrict__ w_gp4,  // (64) float4
    const f32x4*  __restrict__ b_gp4,
    const float*  __restrict__ tbl,    // (TPTS+1)
    float* __restrict__ gvbuf,         // (BT*NG) out: group means
    float* __restrict__ out)
{
    const int lane = threadIdx.x & 63;
    const int wv   = threadIdx.x >> 6;
    const size_t row0 = ((size_t)blockIdx.x * 4 + wv) * 4;  // 4 rows per wave

    __shared__ float sx[4][4][68];     // per-wave staging (+pad, 16B-aligned)
    {
        const f32x4 xl = ((const f32x4*)x)[row0 * 16 + lane];
        const int r = lane >> 4, c = lane & 15;
        *(f32x4*)&sx[wv][r][c * 4] = xl;       // intra-wave only: no barrier
    }

    const int j   = lane >> 4;         // row within wave
    const int g   = lane & 15;         // group
    const int sub = g & 3;             // segment sizes [1,3,5,7] tiled x4
    const int sz  = 2 * sub + 1;
    const int beg = ((g >> 2) << 4) + sub * sub;   // {0,1,4,9}+16*chunk

    float s = 0.0f;
    #pragma unroll
    for (int i = 0; i < 7; ++i)
        if (i < sz) s += sx[wv][j][beg + i];
    const float gv = s * __builtin_amdgcn_rcpf((float)sz);

    // gv out (plain store: kernel 3 re-reads it through L2/L3)
    gvbuf[row0 * NG + lane] = gv;

    // ---- score via table lookup + lerp ----
    float idxf = fminf(fmaxf((gv - ZLO) * ZSCALE, 0.0f), (float)TPTS - 0.001f);
    const int   i0 = (int)idxf;
    const float fr = idxf - (float)i0;
    const float t0 = tbl[i0], t1 = tbl[i0 + 1];
    const float score = fmaf(fr, t1 - t0, t0);

    // ---- softmax across the 16-lane group ----
    float m = score;
    m = fmaxf(m, __shfl_xor(m, 1, 64));
    m = fmaxf(m, __shfl_xor(m, 2, 64));
    m = fmaxf(m, __shfl_xor(m, 4, 64));
    m = fmaxf(m, __shfl_xor(m, 8, 64));
    const float e = __expf(score - m);
    float ssum = e;
    ssum += __shfl_xor(ssum, 1, 64);
    ssum += __shfl_xor(ssum, 2, 64);
    ssum += __shfl_xor(ssum, 4, 64);
    ssum += __shfl_xor(ssum, 8, 64);
    const float w = e / ssum;          // weight for (row j, group g)

    __builtin_nontemporal_store(w, out + WT_OFF + row0 * NG + lane);

    // ---- dot_j = sum_g wt_g*gv_g ; visit = dot*w_gp + b_gp (exact) ----
    float d = w * gv;
    d += __shfl_xor(d, 1, 64);
    d += __shfl_xor(d, 2, 64);
    d += __shfl_xor(d, 4, 64);
    d += __shfl_xor(d, 8, 64);

    const f32x4 wg = w_gp4[lane];
    const f32x4 bg = b_gp4[lane];
    #pragma unroll
    for (int jj = 0; jj < 4; ++jj) {
        const float dj = rln(d, jj * 16);
        f32x4 vis;
        vis.x = fmaf(dj, wg.x, bg.x);
        vis.y = fmaf(dj, wg.y, bg.y);
        vis.z = fmaf(dj, wg.z, bg.z);
        vis.w = fmaf(dj, wg.w, bg.w);
        __builtin_nontemporal_store(vis,
            (f32x4*)(out + (row0 + jj) * HID + 4 * lane));
    }
}

// ---- kernel 3: pure fill-shaped token sweep. Grid-stride, wave-chunk = one
// (row,g) 1 KB store; consecutive waves -> consecutive addresses -> one dense
// device-wide front. tok[c*256 + h] = gvbuf[c]*w_gp[h] + b_gp[h].
__global__ __launch_bounds__(256) void token_sweep(
    const float*  __restrict__ gvbuf,  // (BT*NG)
    const f32x4*  __restrict__ w_gp4,
    const f32x4*  __restrict__ b_gp4,
    float* __restrict__ out)
{
    const int lane = threadIdx.x & 63;
    const int wv   = threadIdx.x >> 6;
    const f32x4 wg = w_gp4[lane];
    const f32x4 bg = b_gp4[lane];
    constexpr size_t NW = (size_t)GRID3 * 4;        // 8192 waves
    size_t c = (size_t)blockIdx.x * 4 + wv;
    float* __restrict__ tok = out + TOK_OFF + 4 * lane;

    float gvv = gvbuf[c];                           // prefetched
    #pragma unroll 1
    for (; c < NCHUNK; ) {
        const size_t cn = c + NW;
        float nxt = 0.0f;
        if (cn < NCHUNK) nxt = gvbuf[cn];           // issue next load early
        f32x4 t;
        t.x = fmaf(gvv, wg.x, bg.x);
        t.y = fmaf(gvv, wg.y, bg.y);
        t.z = fmaf(gvv, wg.z, bg.z);
        t.w = fmaf(gvv, wg.w, bg.w);
        __builtin_nontemporal_store(t, (f32x4*)(tok + c * HID));
        gvv = nxt;
        c = cn;
    }
}

extern "C" void kernel_launch(void* const* d_in, const int* in_sizes, int n_in,
                              void* d_out, int out_size, void* d_ws, size_t ws_size,
                              hipStream_t stream) {
    (void)in_sizes; (void)n_in; (void)out_size; (void)ws_size;
    const float* x    = (const float*)d_in[0];
    const float* w_gp = (const float*)d_in[1];
    const float* b_gp = (const float*)d_in[2];
    const float* w_sp = (const float*)d_in[3];
    const float* b_sp = (const float*)d_in[4];
    float* out = (float*)d_out;
    float* tbl   = (float*)d_ws;                          // 8196 B
    float* gvbuf = (float*)((char*)d_ws + 16384);         // 4 MB; needs ws>=4.3MB

    build_table<<<dim3(TPTS + 1), dim3(256), 0, stream>>>(
        w_gp, b_gp, w_sp, b_sp, tbl);

    compute_kernel<<<dim3((unsigned)(BT / 16)), dim3(256), 0, stream>>>(
        x, (const f32x4*)w_gp, (const f32x4*)b_gp, tbl, gvbuf, out);

    token_sweep<<<dim3(GRID3), dim3(256), 0, stream>>>(
        gvbuf, (const f32x4*)w_gp, (const f32x4*)b_gp, out);
}